// Round 2
// baseline (732.273 us; speedup 1.0000x reference)
//
#include <hip/hip_runtime.h>
#include <hip/hip_bf16.h>

// Pipeline (N=50000, E=1.6M, D=16, NK=2):
//   CSR build: hist(dst) -> scan -> scatter packed (src, k0, k1) sorted by dst
//   conv1+mlp1 fused: h1[N,32] = l2norm(relu(conv(x) @ W1 + b1)), 1 wave/node
//   conv2:            h2[N,64] = conv(h1), 1 wave/node, no atomics
//   mlp2:             out = l2norm(relu(h2@W2a+b2a)@W2b + b2b)

#define EPSV 1e-12f

// ---- detect whether edge_index buffer is int64 (odd int32 words all zero) ----
__global__ void detect_i64_kernel(const int* ei, int* flag) {
    int lane = threadIdx.x;
    int nonzero = 0;
    for (int i = lane; i < 1024; i += 64) {
        if (ei[2 * i + 1] != 0) nonzero = 1;
    }
    unsigned long long b = __ballot(nonzero);
    if (lane == 0) *flag = (b == 0ull) ? 1 : 0;   // 1 => int64 layout
}

__device__ __forceinline__ void load_edge(const int* ei, int e, int E, int flag,
                                          int& src, int& dst) {
    if (flag) {            // int64 storage: low words at even int32 indices
        src = ei[2 * e];
        dst = ei[2 * E + 2 * e];
    } else {               // int32 storage
        src = ei[e];
        dst = ei[E + e];
    }
}

// ---- histogram of dst ----
__global__ void hist_kernel(const int* __restrict__ ei,
                            const int* __restrict__ flagp,
                            int* __restrict__ counts, int E) {
    int e = blockIdx.x * 256 + threadIdx.x;
    if (e >= E) return;
    int flag = *flagp;
    int src, dst;
    load_edge(ei, e, E, flag, src, dst);
    (void)src;
    atomicAdd(&counts[dst], 1);
}

// ---- single-block exclusive scan: off[i] = sum_{j<i} counts[j]; cursor=off ----
__global__ void scan_kernel(const int* __restrict__ counts,
                            int* __restrict__ off,
                            int* __restrict__ cursor, int N) {
    __shared__ int s[1024];
    int t = threadIdx.x;
    const int CH = (N + 1023) >> 10;
    int base = t * CH;
    int local = 0;
    for (int j = 0; j < CH; j++) {
        int i = base + j;
        if (i < N) local += counts[i];
    }
    s[t] = local;
    __syncthreads();
    for (int d = 1; d < 1024; d <<= 1) {
        int add = (t >= d) ? s[t - d] : 0;
        __syncthreads();
        s[t] += add;
        __syncthreads();
    }
    int run = s[t] - local;   // exclusive prefix of this thread's chunk
    for (int j = 0; j < CH; j++) {
        int i = base + j;
        if (i < N) {
            off[i] = run;
            cursor[i] = run;
            run += counts[i];
        }
    }
}

// ---- scatter edges into dst-sorted order, packing (src, k0, k1) ----
__global__ void scatter_kernel(const float* __restrict__ K,
                               const int* __restrict__ ei,
                               const int* __restrict__ flagp,
                               int* __restrict__ cursor,
                               int* __restrict__ srcS,
                               float2* __restrict__ kS, int E) {
    int e = blockIdx.x * 256 + threadIdx.x;
    if (e >= E) return;
    int flag = *flagp;
    int src, dst;
    load_edge(ei, e, E, flag, src, dst);
    int pos = atomicAdd(&cursor[dst], 1);
    srcS[pos] = src;
    kS[pos] = make_float2(K[e], K[E + e]);
}

// ---- conv1 + MLP1 fused: one wave per node ----
// conv: out row r = k*16+ch; lanes split edges by half-wave, combine via xor(32)
// mlp1: h1 = l2norm(relu(row @ W1 + b1))
__global__ void conv1_mlp1_kernel(const float* __restrict__ x,
                                  const int* __restrict__ srcS,
                                  const float2* __restrict__ kS,
                                  const int* __restrict__ off,
                                  const int* __restrict__ counts,
                                  const float* __restrict__ W1,
                                  const float* __restrict__ b1,
                                  float* __restrict__ h1, int N) {
    __shared__ float w[32 * 32];
    __shared__ float bsh[32];
    for (int i = threadIdx.x; i < 1024; i += 256) w[i] = W1[i];
    if (threadIdx.x < 32) bsh[threadIdx.x] = b1[threadIdx.x];
    __syncthreads();

    int wid = threadIdx.x >> 6;
    int lane = threadIdx.x & 63;
    int node = blockIdx.x * 4 + wid;
    if (node >= N) return;

    int ch = lane & 15;
    int k = (lane >> 4) & 1;
    int half = lane >> 5;
    int start = off[node];
    int deg = counts[node];

    float acc = 0.0f;
    for (int j = half; j < deg; j += 2) {
        int p = start + j;
        int src = srcS[p];
        float2 kk = kS[p];
        float kv = k ? kk.y : kk.x;
        acc += kv * x[src * 16 + ch];
    }
    acc += __shfl_xor(acc, 32, 64);
    // lanes 0-31 hold row element `lane`; lanes 32-63 mirror it.
    float v = acc;

    int col = lane & 31;
    float o = half ? 0.0f : bsh[col];
#pragma unroll
    for (int i = 0; i < 16; i++) {
        int idx = half * 16 + i;
        o += __shfl(v, idx, 64) * w[idx * 32 + col];
    }
    o += __shfl_xor(o, 32, 64);
    o = fmaxf(o, 0.0f);

    float ss = o * o;
#pragma unroll
    for (int m = 16; m >= 1; m >>= 1) ss += __shfl_xor(ss, m, 64);
    float nrm = sqrtf(ss);
    if (half == 0) h1[node * 32 + col] = o / fmaxf(nrm, EPSV);
}

// ---- conv2: one wave per node, 64 output channels ----
__global__ void conv2_gather_kernel(const float* __restrict__ h1,
                                    const int* __restrict__ srcS,
                                    const float2* __restrict__ kS,
                                    const int* __restrict__ off,
                                    const int* __restrict__ counts,
                                    float* __restrict__ h2, int N) {
    int wid = threadIdx.x >> 6;
    int lane = threadIdx.x & 63;
    int node = blockIdx.x * 4 + wid;
    if (node >= N) return;

    int ch = lane & 31;
    int k = lane >> 5;
    int start = off[node];
    int deg = counts[node];

    float acc = 0.0f;
    for (int j = 0; j < deg; j++) {
        int p = start + j;
        int src = srcS[p];
        float2 kk = kS[p];
        float kv = k ? kk.y : kk.x;
        acc += kv * h1[src * 32 + ch];
    }
    h2[node * 64 + k * 32 + ch] = acc;
}

// ---- MLP2: out = l2norm(relu(h2@W2a+b2a)@W2b + b2b). 64 lanes/node ----
__global__ void mlp2_kernel(const float* __restrict__ h2,
                            const float* __restrict__ W2a,
                            const float* __restrict__ b2a,
                            const float* __restrict__ W2b,
                            const float* __restrict__ b2b,
                            float* __restrict__ out, int N) {
    __shared__ float wa[64 * 128];
    __shared__ float wb[128 * 64];
    __shared__ float ba[128];
    __shared__ float bb[64];
    for (int i = threadIdx.x; i < 8192; i += 256) {
        wa[i] = W2a[i];
        wb[i] = W2b[i];
    }
    if (threadIdx.x < 128) ba[threadIdx.x] = b2a[threadIdx.x];
    if (threadIdx.x < 64) bb[threadIdx.x] = b2b[threadIdx.x];
    __syncthreads();
    int w = threadIdx.x >> 6;
    int lane = threadIdx.x & 63;
    int node = blockIdx.x * 4 + w;
    if (node >= N) return;
    float v = h2[node * 64 + lane];
    float hA = ba[lane];
    float hB = ba[lane + 64];
#pragma unroll
    for (int i = 0; i < 64; i++) {
        float xi = __shfl(v, i, 64);
        hA += xi * wa[i * 128 + lane];
        hB += xi * wa[i * 128 + 64 + lane];
    }
    hA = fmaxf(hA, 0.0f);
    hB = fmaxf(hB, 0.0f);
    float o = bb[lane];
#pragma unroll
    for (int j = 0; j < 64; j++) {
        o += __shfl(hA, j, 64) * wb[j * 64 + lane];
        o += __shfl(hB, j, 64) * wb[(64 + j) * 64 + lane];
    }
    float ss = o * o;
#pragma unroll
    for (int m = 32; m >= 1; m >>= 1) ss += __shfl_xor(ss, m, 64);
    float nrm = sqrtf(ss);
    out[node * 64 + lane] = o / fmaxf(nrm, EPSV);
}

extern "C" void kernel_launch(void* const* d_in, const int* in_sizes, int n_in,
                              void* d_out, int out_size, void* d_ws, size_t ws_size,
                              hipStream_t stream) {
    const float* x   = (const float*)d_in[0];
    const float* K   = (const float*)d_in[1];
    const int*   ei  = (const int*)d_in[2];
    const float* W1  = (const float*)d_in[3];
    const float* b1  = (const float*)d_in[4];
    const float* W2a = (const float*)d_in[5];
    const float* b2a = (const float*)d_in[6];
    const float* W2b = (const float*)d_in[7];
    const float* b2b = (const float*)d_in[8];
    float* out = (float*)d_out;

    const int D  = 16;
    const int NK = 2;
    const int N  = in_sizes[0] / D;        // 50000
    const int E  = in_sizes[1] / NK;       // 1600000

    // workspace layout (4-byte units, 8B-aligned where needed):
    //   h1[N*32] | h2[N*64] | kS[2*E] (float2) | srcS[E] | counts[N] |
    //   off[N] | cursor[N] | flag[1]
    float* h1     = (float*)d_ws;
    float* h2     = h1 + (size_t)N * 32;
    float2* kS    = (float2*)(h2 + (size_t)N * 64);
    int* srcS     = (int*)(kS + (size_t)E);
    int* counts   = srcS + (size_t)E;
    int* off      = counts + N;
    int* cursor   = off + N;
    int* flag     = cursor + N;

    hipMemsetAsync(counts, 0, (size_t)N * sizeof(int), stream);
    detect_i64_kernel<<<1, 64, 0, stream>>>(ei, flag);

    int eblocks = (E + 255) / 256;
    hist_kernel<<<eblocks, 256, 0, stream>>>(ei, flag, counts, E);
    scan_kernel<<<1, 1024, 0, stream>>>(counts, off, cursor, N);
    scatter_kernel<<<eblocks, 256, 0, stream>>>(K, ei, flag, cursor, srcS, kS, E);

    int nblocks = (N + 3) / 4;
    conv1_mlp1_kernel<<<nblocks, 256, 0, stream>>>(x, srcS, kS, off, counts,
                                                   W1, b1, h1, N);
    conv2_gather_kernel<<<nblocks, 256, 0, stream>>>(h1, srcS, kS, off, counts,
                                                     h2, N);
    mlp2_kernel<<<nblocks, 256, 0, stream>>>(h2, W2a, b2a, W2b, b2b, out, N);
}

// Round 3
// 473.633 us; speedup vs baseline: 1.5461x; 1.5461x over previous
//
#include <hip/hip_runtime.h>
#include <hip/hip_bf16.h>

// Pipeline (N=50000, E=1.6M, D=16, NK=2):
//   CSR build: hist(dst) -> hierarchical scan -> scatter packed (src,k0,k1)
//   conv1+mlp1 fused: h1[N,32] = l2norm(relu(conv(x) @ W1 + b1)), 1 wave/node
//   conv2:            h2[N,64] = conv(h1), 1 wave/node, no atomics
//   mlp2:             out = l2norm(relu(h2@W2a+b2a)@W2b + b2b)  [reg-tiled GEMM]

#define EPSV 1e-12f

// ---- detect whether edge_index buffer is int64 (odd int32 words all zero) ----
__global__ void detect_i64_kernel(const int* ei, int* flag) {
    int lane = threadIdx.x;
    int nonzero = 0;
    for (int i = lane; i < 1024; i += 64) {
        if (ei[2 * i + 1] != 0) nonzero = 1;
    }
    unsigned long long b = __ballot(nonzero);
    if (lane == 0) *flag = (b == 0ull) ? 1 : 0;   // 1 => int64 layout
}

__device__ __forceinline__ void load_edge(const int* ei, int e, int E, int flag,
                                          int& src, int& dst) {
    if (flag) {            // int64 storage: low words at even int32 indices
        src = ei[2 * e];
        dst = ei[2 * E + 2 * e];
    } else {               // int32 storage
        src = ei[e];
        dst = ei[E + e];
    }
}

// ---- histogram of dst ----
__global__ void hist_kernel(const int* __restrict__ ei,
                            const int* __restrict__ flagp,
                            int* __restrict__ counts, int E) {
    int e = blockIdx.x * 256 + threadIdx.x;
    if (e >= E) return;
    int flag = *flagp;
    int src, dst;
    load_edge(ei, e, E, flag, src, dst);
    (void)src;
    atomicAdd(&counts[dst], 1);
}

// ---- hierarchical scan: per-block exclusive partials + block sums ----
__global__ void scan1_kernel(const int* __restrict__ counts,
                             int* __restrict__ partial,
                             int* __restrict__ bsum, int N) {
    __shared__ int ws[4];
    int i = blockIdx.x * 256 + threadIdx.x;
    int v = (i < N) ? counts[i] : 0;
    int lane = threadIdx.x & 63;
    int wid = threadIdx.x >> 6;
    int s = v;
#pragma unroll
    for (int d = 1; d < 64; d <<= 1) {
        int t = __shfl_up(s, d, 64);
        if (lane >= d) s += t;
    }
    if (lane == 63) ws[wid] = s;
    __syncthreads();
    if (threadIdx.x == 0) {
        int r = 0;
        for (int w = 0; w < 4; w++) { int t = ws[w]; ws[w] = r; r += t; }
        bsum[blockIdx.x] = r;
    }
    __syncthreads();
    if (i < N) partial[i] = (s - v) + ws[wid];
}

// ---- scan block sums (NB <= 256) ----
__global__ void scan2_kernel(int* __restrict__ bsum, int NB) {
    __shared__ int ws[4];
    int t = threadIdx.x;
    int v = (t < NB) ? bsum[t] : 0;
    int lane = t & 63;
    int wid = t >> 6;
    int s = v;
#pragma unroll
    for (int d = 1; d < 64; d <<= 1) {
        int u = __shfl_up(s, d, 64);
        if (lane >= d) s += u;
    }
    if (lane == 63) ws[wid] = s;
    __syncthreads();
    if (t == 0) {
        int r = 0;
        for (int w = 0; w < 4; w++) { int u = ws[w]; ws[w] = r; r += u; }
    }
    __syncthreads();
    if (t < NB) bsum[t] = (s - v) + ws[wid];   // exclusive block offsets
}

// ---- combine: off / cursor ----
__global__ void scan3_kernel(const int* __restrict__ partial,
                             const int* __restrict__ bsum,
                             int* __restrict__ off,
                             int* __restrict__ cursor, int N) {
    int i = blockIdx.x * 256 + threadIdx.x;
    if (i >= N) return;
    int o = partial[i] + bsum[i >> 8];
    off[i] = o;
    cursor[i] = o;
}

// ---- scatter edges into dst-sorted order, packing (src, k0, k1) ----
__global__ void scatter_kernel(const float* __restrict__ K,
                               const int* __restrict__ ei,
                               const int* __restrict__ flagp,
                               int* __restrict__ cursor,
                               int* __restrict__ srcS,
                               float2* __restrict__ kS, int E) {
    int e = blockIdx.x * 256 + threadIdx.x;
    if (e >= E) return;
    int flag = *flagp;
    int src, dst;
    load_edge(ei, e, E, flag, src, dst);
    int pos = atomicAdd(&cursor[dst], 1);
    srcS[pos] = src;
    kS[pos] = make_float2(K[e], K[E + e]);
}

// ---- conv1 + MLP1 fused: one wave per node ----
__global__ void conv1_mlp1_kernel(const float* __restrict__ x,
                                  const int* __restrict__ srcS,
                                  const float2* __restrict__ kS,
                                  const int* __restrict__ off,
                                  const int* __restrict__ counts,
                                  const float* __restrict__ W1,
                                  const float* __restrict__ b1,
                                  float* __restrict__ h1, int N) {
    __shared__ float w[32 * 32];
    __shared__ float bsh[32];
    for (int i = threadIdx.x; i < 1024; i += 256) w[i] = W1[i];
    if (threadIdx.x < 32) bsh[threadIdx.x] = b1[threadIdx.x];
    __syncthreads();

    int wid = threadIdx.x >> 6;
    int lane = threadIdx.x & 63;
    int node = blockIdx.x * 4 + wid;
    if (node >= N) return;

    int ch = lane & 15;
    int k = (lane >> 4) & 1;
    int half = lane >> 5;
    int start = off[node];
    int deg = counts[node];

    float acc = 0.0f;
    for (int j = half; j < deg; j += 2) {
        int p = start + j;
        int src = srcS[p];
        float2 kk = kS[p];
        float kv = k ? kk.y : kk.x;
        acc += kv * x[src * 16 + ch];
    }
    acc += __shfl_xor(acc, 32, 64);
    float v = acc;

    int col = lane & 31;
    float o = half ? 0.0f : bsh[col];
#pragma unroll
    for (int i = 0; i < 16; i++) {
        int idx = half * 16 + i;
        o += __shfl(v, idx, 64) * w[idx * 32 + col];
    }
    o += __shfl_xor(o, 32, 64);
    o = fmaxf(o, 0.0f);

    float ss = o * o;
#pragma unroll
    for (int m = 16; m >= 1; m >>= 1) ss += __shfl_xor(ss, m, 64);
    float nrm = sqrtf(ss);
    if (half == 0) h1[node * 32 + col] = o / fmaxf(nrm, EPSV);
}

// ---- conv2: one wave per node, 64 output channels ----
__global__ void conv2_gather_kernel(const float* __restrict__ h1,
                                    const int* __restrict__ srcS,
                                    const float2* __restrict__ kS,
                                    const int* __restrict__ off,
                                    const int* __restrict__ counts,
                                    float* __restrict__ h2, int N) {
    int wid = threadIdx.x >> 6;
    int lane = threadIdx.x & 63;
    int node = blockIdx.x * 4 + wid;
    if (node >= N) return;

    int ch = lane & 31;
    int k = lane >> 5;
    int start = off[node];
    int deg = counts[node];

    float acc = 0.0f;
    for (int j = 0; j < deg; j++) {
        int p = start + j;
        int src = srcS[p];
        float2 kk = kS[p];
        float kv = k ? kk.y : kk.x;
        acc += kv * h1[src * 32 + ch];
    }
    h2[node * 64 + k * 32 + ch] = acc;
}

// ---- MLP2 register-tiled: 64 nodes/block, 256 threads ----
// GEMM1: H[64,128] = relu(X[64,64] @ W2a + b2a)
// GEMM2: O[64,64]  = H @ W2b + b2b;  out = l2norm(O) per row
__global__ __launch_bounds__(256) void mlp2_kernel(
        const float* __restrict__ h2,
        const float* __restrict__ W2a,
        const float* __restrict__ b2a,
        const float* __restrict__ W2b,
        const float* __restrict__ b2b,
        float* __restrict__ out, int N) {
    __shared__ float xs[64 * 68];    // xs[k*68 + n]: transposed X, k in [0,64)
    __shared__ float hs[128 * 68];   // hs[k*68 + n]: transposed H, k in [0,128)

    int tid = threadIdx.x;
    int n0 = blockIdx.x * 64;

    // load + transpose X = h2[n0..n0+63][0..63]
#pragma unroll
    for (int it = 0; it < 4; ++it) {
        int idx = tid + it * 256;        // 0..1023
        int n = idx >> 4;                // node within block
        int c4 = (idx & 15) * 4;         // channel group
        float4 v = make_float4(0.f, 0.f, 0.f, 0.f);
        if (n0 + n < N) v = *(const float4*)&h2[(size_t)(n0 + n) * 64 + c4];
        xs[(c4 + 0) * 68 + n] = v.x;
        xs[(c4 + 1) * 68 + n] = v.y;
        xs[(c4 + 2) * 68 + n] = v.z;
        xs[(c4 + 3) * 68 + n] = v.w;
    }
    __syncthreads();

    int rg = tid >> 4;     // row group: rows rg*4 .. rg*4+3
    int cg = tid & 15;     // col group

    // GEMM1: cols cg*8 .. cg*8+7
    float acc[4][8];
#pragma unroll
    for (int j = 0; j < 4; j++)
#pragma unroll
        for (int i = 0; i < 8; i++) acc[j][i] = 0.0f;

    for (int k = 0; k < 64; ++k) {
        float4 xv = *(const float4*)&xs[k * 68 + rg * 4];
        float4 w0 = *(const float4*)&W2a[k * 128 + cg * 8];
        float4 w1 = *(const float4*)&W2a[k * 128 + cg * 8 + 4];
        float wv[8] = {w0.x, w0.y, w0.z, w0.w, w1.x, w1.y, w1.z, w1.w};
        float xr[4] = {xv.x, xv.y, xv.z, xv.w};
#pragma unroll
        for (int j = 0; j < 4; j++)
#pragma unroll
            for (int i = 0; i < 8; i++) acc[j][i] += xr[j] * wv[i];
    }

    // bias + relu + store transposed H
#pragma unroll
    for (int i = 0; i < 8; i++) {
        float bi = b2a[cg * 8 + i];
#pragma unroll
        for (int j = 0; j < 4; j++) {
            float hv = fmaxf(acc[j][i] + bi, 0.0f);
            hs[(cg * 8 + i) * 68 + rg * 4 + j] = hv;
        }
    }
    __syncthreads();

    // GEMM2: cols cg*4 .. cg*4+3
    float a2[4][4];
#pragma unroll
    for (int j = 0; j < 4; j++)
#pragma unroll
        for (int i = 0; i < 4; i++) a2[j][i] = 0.0f;

    for (int k = 0; k < 128; ++k) {
        float4 hv = *(const float4*)&hs[k * 68 + rg * 4];
        float4 w = *(const float4*)&W2b[k * 64 + cg * 4];
        float wv[4] = {w.x, w.y, w.z, w.w};
        float hr[4] = {hv.x, hv.y, hv.z, hv.w};
#pragma unroll
        for (int j = 0; j < 4; j++)
#pragma unroll
            for (int i = 0; i < 4; i++) a2[j][i] += hr[j] * wv[i];
    }

#pragma unroll
    for (int i = 0; i < 4; i++) {
        float bi = b2b[cg * 4 + i];
#pragma unroll
        for (int j = 0; j < 4; j++) a2[j][i] += bi;
    }

    // l2norm per row: reduce squares across the 16 cg lanes (consecutive)
#pragma unroll
    for (int j = 0; j < 4; j++) {
        float ss = a2[j][0] * a2[j][0] + a2[j][1] * a2[j][1] +
                   a2[j][2] * a2[j][2] + a2[j][3] * a2[j][3];
#pragma unroll
        for (int m = 1; m < 16; m <<= 1) ss += __shfl_xor(ss, m, 64);
        float invn = 1.0f / fmaxf(sqrtf(ss), EPSV);
        int n = n0 + rg * 4 + j;
        if (n < N) {
            float4 o = make_float4(a2[j][0] * invn, a2[j][1] * invn,
                                   a2[j][2] * invn, a2[j][3] * invn);
            *(float4*)&out[(size_t)n * 64 + cg * 4] = o;
        }
    }
}

extern "C" void kernel_launch(void* const* d_in, const int* in_sizes, int n_in,
                              void* d_out, int out_size, void* d_ws, size_t ws_size,
                              hipStream_t stream) {
    const float* x   = (const float*)d_in[0];
    const float* K   = (const float*)d_in[1];
    const int*   ei  = (const int*)d_in[2];
    const float* W1  = (const float*)d_in[3];
    const float* b1  = (const float*)d_in[4];
    const float* W2a = (const float*)d_in[5];
    const float* b2a = (const float*)d_in[6];
    const float* W2b = (const float*)d_in[7];
    const float* b2b = (const float*)d_in[8];
    float* out = (float*)d_out;

    const int D  = 16;
    const int NK = 2;
    const int N  = in_sizes[0] / D;        // 50000
    const int E  = in_sizes[1] / NK;       // 1600000
    const int NB = (N + 255) / 256;        // scan blocks (<=256)

    // workspace layout (4-byte units):
    //   h1[N*32] | h2[N*64] | kS[2*E] (float2) | srcS[E] | counts[N] |
    //   off[N] | cursor[N] | partial[N] | bsum[256] | flag[1]
    float* h1     = (float*)d_ws;
    float* h2     = h1 + (size_t)N * 32;
    float2* kS    = (float2*)(h2 + (size_t)N * 64);
    int* srcS     = (int*)(kS + (size_t)E);
    int* counts   = srcS + (size_t)E;
    int* off      = counts + N;
    int* cursor   = off + N;
    int* partial  = cursor + N;
    int* bsum     = partial + N;
    int* flag     = bsum + 256;

    hipMemsetAsync(counts, 0, (size_t)N * sizeof(int), stream);
    detect_i64_kernel<<<1, 64, 0, stream>>>(ei, flag);

    int eblocks = (E + 255) / 256;
    hist_kernel<<<eblocks, 256, 0, stream>>>(ei, flag, counts, E);
    scan1_kernel<<<NB, 256, 0, stream>>>(counts, partial, bsum, N);
    scan2_kernel<<<1, 256, 0, stream>>>(bsum, NB);
    scan3_kernel<<<NB, 256, 0, stream>>>(partial, bsum, off, cursor, N);
    scatter_kernel<<<eblocks, 256, 0, stream>>>(K, ei, flag, cursor, srcS, kS, E);

    int nblocks = (N + 3) / 4;
    conv1_mlp1_kernel<<<nblocks, 256, 0, stream>>>(x, srcS, kS, off, counts,
                                                   W1, b1, h1, N);
    conv2_gather_kernel<<<nblocks, 256, 0, stream>>>(h1, srcS, kS, off, counts,
                                                     h2, N);
    int mblocks = (N + 63) / 64;
    mlp2_kernel<<<mblocks, 256, 0, stream>>>(h2, W2a, b2a, W2b, b2b, out, N);
}

// Round 4
// 361.816 us; speedup vs baseline: 2.0239x; 1.3090x over previous
//
#include <hip/hip_runtime.h>
#include <hip/hip_bf16.h>

// Pipeline (N=50000, E=1.6M, D=16, NK=2):
//   CSR build: hist(dst) -> hierarchical scan -> scatter packed (src,k0,k1)
//   conv1+mlp1 fused: h1[N,32] = l2norm(relu(conv(x) @ W1 + b1)), half-wave/node
//   conv2:            h2[N,64] = conv(h1), 1 wave/node, unroll-4 gather
//   mlp2:             out = l2norm(relu(h2@W2a+b2a)@W2b + b2b)  [reg-tiled GEMM]

#define EPSV 1e-12f

// ---- detect whether edge_index buffer is int64 (odd int32 words all zero) ----
__global__ void detect_i64_kernel(const int* ei, int* flag) {
    int lane = threadIdx.x;
    int nonzero = 0;
    for (int i = lane; i < 1024; i += 64) {
        if (ei[2 * i + 1] != 0) nonzero = 1;
    }
    unsigned long long b = __ballot(nonzero);
    if (lane == 0) *flag = (b == 0ull) ? 1 : 0;   // 1 => int64 layout
}

__device__ __forceinline__ void load_edge(const int* ei, int e, int E, int flag,
                                          int& src, int& dst) {
    if (flag) {            // int64 storage: low words at even int32 indices
        src = ei[2 * e];
        dst = ei[2 * E + 2 * e];
    } else {               // int32 storage
        src = ei[e];
        dst = ei[E + e];
    }
}

// ---- histogram of dst ----
__global__ void hist_kernel(const int* __restrict__ ei,
                            const int* __restrict__ flagp,
                            int* __restrict__ counts, int E) {
    int e = blockIdx.x * 256 + threadIdx.x;
    if (e >= E) return;
    int flag = *flagp;
    int src, dst;
    load_edge(ei, e, E, flag, src, dst);
    (void)src;
    atomicAdd(&counts[dst], 1);
}

// ---- hierarchical scan: per-block exclusive partials + block sums ----
__global__ void scan1_kernel(const int* __restrict__ counts,
                             int* __restrict__ partial,
                             int* __restrict__ bsum, int N) {
    __shared__ int ws[4];
    int i = blockIdx.x * 256 + threadIdx.x;
    int v = (i < N) ? counts[i] : 0;
    int lane = threadIdx.x & 63;
    int wid = threadIdx.x >> 6;
    int s = v;
#pragma unroll
    for (int d = 1; d < 64; d <<= 1) {
        int t = __shfl_up(s, d, 64);
        if (lane >= d) s += t;
    }
    if (lane == 63) ws[wid] = s;
    __syncthreads();
    if (threadIdx.x == 0) {
        int r = 0;
        for (int w = 0; w < 4; w++) { int t = ws[w]; ws[w] = r; r += t; }
        bsum[blockIdx.x] = r;
    }
    __syncthreads();
    if (i < N) partial[i] = (s - v) + ws[wid];
}

// ---- scan block sums (NB <= 256) ----
__global__ void scan2_kernel(int* __restrict__ bsum, int NB) {
    __shared__ int ws[4];
    int t = threadIdx.x;
    int v = (t < NB) ? bsum[t] : 0;
    int lane = t & 63;
    int wid = t >> 6;
    int s = v;
#pragma unroll
    for (int d = 1; d < 64; d <<= 1) {
        int u = __shfl_up(s, d, 64);
        if (lane >= d) s += u;
    }
    if (lane == 63) ws[wid] = s;
    __syncthreads();
    if (t == 0) {
        int r = 0;
        for (int w = 0; w < 4; w++) { int u = ws[w]; ws[w] = r; r += u; }
    }
    __syncthreads();
    if (t < NB) bsum[t] = (s - v) + ws[wid];   // exclusive block offsets
}

// ---- combine: off / cursor ----
__global__ void scan3_kernel(const int* __restrict__ partial,
                             const int* __restrict__ bsum,
                             int* __restrict__ off,
                             int* __restrict__ cursor, int N) {
    int i = blockIdx.x * 256 + threadIdx.x;
    if (i >= N) return;
    int o = partial[i] + bsum[i >> 8];
    off[i] = o;
    cursor[i] = o;
}

// ---- scatter edges into dst-sorted order, packing (src, k0, k1) ----
__global__ void scatter_kernel(const float* __restrict__ K,
                               const int* __restrict__ ei,
                               const int* __restrict__ flagp,
                               int* __restrict__ cursor,
                               int* __restrict__ srcS,
                               float2* __restrict__ kS, int E) {
    int e = blockIdx.x * 256 + threadIdx.x;
    if (e >= E) return;
    int flag = *flagp;
    int src, dst;
    load_edge(ei, e, E, flag, src, dst);
    int pos = atomicAdd(&cursor[dst], 1);
    srcS[pos] = src;
    kS[pos] = make_float2(K[e], K[E + e]);
}

// ---- conv1 + MLP1 fused: one HALF-WAVE (32 lanes) per node ----
// lane = k*16 + ch exactly matches kernel-major row layout [k*16+ch].
__global__ void conv1_mlp1_kernel(const float* __restrict__ x,
                                  const int* __restrict__ srcS,
                                  const float2* __restrict__ kS,
                                  const int* __restrict__ off,
                                  const int* __restrict__ counts,
                                  const float* __restrict__ W1,
                                  const float* __restrict__ b1,
                                  float* __restrict__ h1, int N) {
    __shared__ float w[32 * 32];
    __shared__ float bsh[32];
    for (int i = threadIdx.x; i < 1024; i += 256) w[i] = W1[i];
    if (threadIdx.x < 32) bsh[threadIdx.x] = b1[threadIdx.x];
    __syncthreads();

    int hw = threadIdx.x >> 5;        // half-wave 0..7
    int lane = threadIdx.x & 31;
    int node = blockIdx.x * 8 + hw;
    if (node >= N) return;

    int ch = lane & 15;
    int kq = lane >> 4;               // 0 or 1
    int start = off[node];
    int deg = counts[node];

    float acc = 0.0f;
    int j = 0;
    for (; j + 4 <= deg; j += 4) {
        int p = start + j;
        int s0 = srcS[p + 0];
        int s1 = srcS[p + 1];
        int s2 = srcS[p + 2];
        int s3 = srcS[p + 3];
        float2 ka = kS[p + 0];
        float2 kb = kS[p + 1];
        float2 kc = kS[p + 2];
        float2 kd = kS[p + 3];
        float x0 = x[s0 * 16 + ch];
        float x1 = x[s1 * 16 + ch];
        float x2 = x[s2 * 16 + ch];
        float x3 = x[s3 * 16 + ch];
        acc += (kq ? ka.y : ka.x) * x0;
        acc += (kq ? kb.y : kb.x) * x1;
        acc += (kq ? kc.y : kc.x) * x2;
        acc += (kq ? kd.y : kd.x) * x3;
    }
    for (; j < deg; ++j) {
        int p = start + j;
        int s = srcS[p];
        float2 kk = kS[p];
        acc += (kq ? kk.y : kk.x) * x[s * 16 + ch];
    }

    // MLP1: o = relu(row @ W1 + b1); row element `lane` is in acc
    float o = bsh[lane];
#pragma unroll
    for (int i = 0; i < 32; i++) o += __shfl(acc, i, 32) * w[i * 32 + lane];
    o = fmaxf(o, 0.0f);

    float ss = o * o;
#pragma unroll
    for (int m = 16; m >= 1; m >>= 1) ss += __shfl_xor(ss, m, 32);
    float nrm = sqrtf(ss);
    h1[node * 32 + lane] = o / fmaxf(nrm, EPSV);
}

// ---- conv2: one wave per node, 64 output channels, unroll-4 gather ----
__global__ void conv2_gather_kernel(const float* __restrict__ h1,
                                    const int* __restrict__ srcS,
                                    const float2* __restrict__ kS,
                                    const int* __restrict__ off,
                                    const int* __restrict__ counts,
                                    float* __restrict__ h2, int N) {
    int wid = threadIdx.x >> 6;
    int lane = threadIdx.x & 63;
    int node = blockIdx.x * 4 + wid;
    if (node >= N) return;

    int ch = lane & 31;
    int kq = lane >> 5;
    int start = off[node];
    int deg = counts[node];

    float acc = 0.0f;
    int j = 0;
    for (; j + 4 <= deg; j += 4) {
        int p = start + j;
        int s0 = srcS[p + 0];
        int s1 = srcS[p + 1];
        int s2 = srcS[p + 2];
        int s3 = srcS[p + 3];
        float2 ka = kS[p + 0];
        float2 kb = kS[p + 1];
        float2 kc = kS[p + 2];
        float2 kd = kS[p + 3];
        float v0 = h1[s0 * 32 + ch];
        float v1 = h1[s1 * 32 + ch];
        float v2 = h1[s2 * 32 + ch];
        float v3 = h1[s3 * 32 + ch];
        acc += (kq ? ka.y : ka.x) * v0;
        acc += (kq ? kb.y : kb.x) * v1;
        acc += (kq ? kc.y : kc.x) * v2;
        acc += (kq ? kd.y : kd.x) * v3;
    }
    for (; j < deg; ++j) {
        int p = start + j;
        int s = srcS[p];
        float2 kk = kS[p];
        acc += (kq ? kk.y : kk.x) * h1[s * 32 + ch];
    }
    h2[node * 64 + kq * 32 + ch] = acc;
}

// ---- MLP2 register-tiled: 64 nodes/block, 256 threads ----
__global__ __launch_bounds__(256) void mlp2_kernel(
        const float* __restrict__ h2,
        const float* __restrict__ W2a,
        const float* __restrict__ b2a,
        const float* __restrict__ W2b,
        const float* __restrict__ b2b,
        float* __restrict__ out, int N) {
    __shared__ float xs[64 * 68];    // xs[k*68 + n]: transposed X
    __shared__ float hs[128 * 68];   // hs[k*68 + n]: transposed H

    int tid = threadIdx.x;
    int n0 = blockIdx.x * 64;

#pragma unroll
    for (int it = 0; it < 4; ++it) {
        int idx = tid + it * 256;
        int n = idx >> 4;
        int c4 = (idx & 15) * 4;
        float4 v = make_float4(0.f, 0.f, 0.f, 0.f);
        if (n0 + n < N) v = *(const float4*)&h2[(size_t)(n0 + n) * 64 + c4];
        xs[(c4 + 0) * 68 + n] = v.x;
        xs[(c4 + 1) * 68 + n] = v.y;
        xs[(c4 + 2) * 68 + n] = v.z;
        xs[(c4 + 3) * 68 + n] = v.w;
    }
    __syncthreads();

    int rg = tid >> 4;
    int cg = tid & 15;

    float acc[4][8];
#pragma unroll
    for (int j = 0; j < 4; j++)
#pragma unroll
        for (int i = 0; i < 8; i++) acc[j][i] = 0.0f;

    for (int k = 0; k < 64; ++k) {
        float4 xv = *(const float4*)&xs[k * 68 + rg * 4];
        float4 w0 = *(const float4*)&W2a[k * 128 + cg * 8];
        float4 w1 = *(const float4*)&W2a[k * 128 + cg * 8 + 4];
        float wv[8] = {w0.x, w0.y, w0.z, w0.w, w1.x, w1.y, w1.z, w1.w};
        float xr[4] = {xv.x, xv.y, xv.z, xv.w};
#pragma unroll
        for (int j = 0; j < 4; j++)
#pragma unroll
            for (int i = 0; i < 8; i++) acc[j][i] += xr[j] * wv[i];
    }

#pragma unroll
    for (int i = 0; i < 8; i++) {
        float bi = b2a[cg * 8 + i];
#pragma unroll
        for (int j = 0; j < 4; j++) {
            float hv = fmaxf(acc[j][i] + bi, 0.0f);
            hs[(cg * 8 + i) * 68 + rg * 4 + j] = hv;
        }
    }
    __syncthreads();

    float a2[4][4];
#pragma unroll
    for (int j = 0; j < 4; j++)
#pragma unroll
        for (int i = 0; i < 4; i++) a2[j][i] = 0.0f;

    for (int k = 0; k < 128; ++k) {
        float4 hv = *(const float4*)&hs[k * 68 + rg * 4];
        float4 w = *(const float4*)&W2b[k * 64 + cg * 4];
        float wv[4] = {w.x, w.y, w.z, w.w};
        float hr[4] = {hv.x, hv.y, hv.z, hv.w};
#pragma unroll
        for (int j = 0; j < 4; j++)
#pragma unroll
            for (int i = 0; i < 4; i++) a2[j][i] += hr[j] * wv[i];
    }

#pragma unroll
    for (int i = 0; i < 4; i++) {
        float bi = b2b[cg * 4 + i];
#pragma unroll
        for (int j = 0; j < 4; j++) a2[j][i] += bi;
    }

#pragma unroll
    for (int j = 0; j < 4; j++) {
        float ss = a2[j][0] * a2[j][0] + a2[j][1] * a2[j][1] +
                   a2[j][2] * a2[j][2] + a2[j][3] * a2[j][3];
#pragma unroll
        for (int m = 1; m < 16; m <<= 1) ss += __shfl_xor(ss, m, 64);
        float invn = 1.0f / fmaxf(sqrtf(ss), EPSV);
        int n = n0 + rg * 4 + j;
        if (n < N) {
            float4 o = make_float4(a2[j][0] * invn, a2[j][1] * invn,
                                   a2[j][2] * invn, a2[j][3] * invn);
            *(float4*)&out[(size_t)n * 64 + cg * 4] = o;
        }
    }
}

extern "C" void kernel_launch(void* const* d_in, const int* in_sizes, int n_in,
                              void* d_out, int out_size, void* d_ws, size_t ws_size,
                              hipStream_t stream) {
    const float* x   = (const float*)d_in[0];
    const float* K   = (const float*)d_in[1];
    const int*   ei  = (const int*)d_in[2];
    const float* W1  = (const float*)d_in[3];
    const float* b1  = (const float*)d_in[4];
    const float* W2a = (const float*)d_in[5];
    const float* b2a = (const float*)d_in[6];
    const float* W2b = (const float*)d_in[7];
    const float* b2b = (const float*)d_in[8];
    float* out = (float*)d_out;

    const int D  = 16;
    const int NK = 2;
    const int N  = in_sizes[0] / D;        // 50000
    const int E  = in_sizes[1] / NK;       // 1600000
    const int NB = (N + 255) / 256;        // scan blocks (<=256)

    // workspace layout (4-byte units):
    //   h1[N*32] | h2[N*64] | kS[2*E] (float2) | srcS[E] | counts[N] |
    //   off[N] | cursor[N] | partial[N] | bsum[256] | flag[1]
    float* h1     = (float*)d_ws;
    float* h2     = h1 + (size_t)N * 32;
    float2* kS    = (float2*)(h2 + (size_t)N * 64);
    int* srcS     = (int*)(kS + (size_t)E);
    int* counts   = srcS + (size_t)E;
    int* off      = counts + N;
    int* cursor   = off + N;
    int* partial  = cursor + N;
    int* bsum     = partial + N;
    int* flag     = bsum + 256;

    hipMemsetAsync(counts, 0, (size_t)N * sizeof(int), stream);
    detect_i64_kernel<<<1, 64, 0, stream>>>(ei, flag);

    int eblocks = (E + 255) / 256;
    hist_kernel<<<eblocks, 256, 0, stream>>>(ei, flag, counts, E);
    scan1_kernel<<<NB, 256, 0, stream>>>(counts, partial, bsum, N);
    scan2_kernel<<<1, 256, 0, stream>>>(bsum, NB);
    scan3_kernel<<<NB, 256, 0, stream>>>(partial, bsum, off, cursor, N);
    scatter_kernel<<<eblocks, 256, 0, stream>>>(K, ei, flag, cursor, srcS, kS, E);

    conv1_mlp1_kernel<<<(N + 7) / 8, 256, 0, stream>>>(x, srcS, kS, off, counts,
                                                       W1, b1, h1, N);
    conv2_gather_kernel<<<(N + 3) / 4, 256, 0, stream>>>(h1, srcS, kS, off,
                                                         counts, h2, N);
    mlp2_kernel<<<(N + 63) / 64, 256, 0, stream>>>(h2, W2a, b2a, W2b, b2b,
                                                   out, N);
}

// Round 5
// 310.918 us; speedup vs baseline: 2.3552x; 1.1637x over previous
//
#include <hip/hip_runtime.h>
#include <hip/hip_bf16.h>

// Pipeline (N=50000, E=1.6M, D=16, NK=2):
//   CSR build: hist(dst) -> hierarchical scan -> two-pass locality scatter:
//     partA: bucket-partition edges by dst>>9 (LDS-staged, coalesced writes)
//     partB: within-bucket dst-sort via per-node cursors (L2-local writes)
//   conv1+mlp1 fused: h1[N,32] = l2norm(relu(conv(x) @ W1 + b1)), half-wave/node
//   conv2:            h2[N,64] = conv(h1), 1 wave/node, unroll-4 gather
//   mlp2:             out = l2norm(relu(h2@W2a+b2a)@W2b + b2b)  [reg-tiled GEMM]

#define EPSV 1e-12f
#define CHUNK 2048      // edges per partA block
#define NBMAX 128       // bucket array size (nbuck = ceil(N/512) <= 128)

// ---- detect whether edge_index buffer is int64 (odd int32 words all zero) ----
__global__ void detect_i64_kernel(const int* ei, int* flag) {
    int lane = threadIdx.x;
    int nonzero = 0;
    for (int i = lane; i < 1024; i += 64) {
        if (ei[2 * i + 1] != 0) nonzero = 1;
    }
    unsigned long long b = __ballot(nonzero);
    if (lane == 0) *flag = (b == 0ull) ? 1 : 0;   // 1 => int64 layout
}

__device__ __forceinline__ void load_edge(const int* ei, int e, int E, int flag,
                                          int& src, int& dst) {
    if (flag) {            // int64 storage: low words at even int32 indices
        src = ei[2 * e];
        dst = ei[2 * E + 2 * e];
    } else {               // int32 storage
        src = ei[e];
        dst = ei[E + e];
    }
}

// ---- histogram of dst ----
__global__ void hist_kernel(const int* __restrict__ ei,
                            const int* __restrict__ flagp,
                            int* __restrict__ counts, int E) {
    int e = blockIdx.x * 256 + threadIdx.x;
    if (e >= E) return;
    int flag = *flagp;
    int src, dst;
    load_edge(ei, e, E, flag, src, dst);
    (void)src;
    atomicAdd(&counts[dst], 1);
}

// ---- hierarchical scan: per-block exclusive partials + block sums ----
__global__ void scan1_kernel(const int* __restrict__ counts,
                             int* __restrict__ partial,
                             int* __restrict__ bsum, int N) {
    __shared__ int ws[4];
    int i = blockIdx.x * 256 + threadIdx.x;
    int v = (i < N) ? counts[i] : 0;
    int lane = threadIdx.x & 63;
    int wid = threadIdx.x >> 6;
    int s = v;
#pragma unroll
    for (int d = 1; d < 64; d <<= 1) {
        int t = __shfl_up(s, d, 64);
        if (lane >= d) s += t;
    }
    if (lane == 63) ws[wid] = s;
    __syncthreads();
    if (threadIdx.x == 0) {
        int r = 0;
        for (int w = 0; w < 4; w++) { int t = ws[w]; ws[w] = r; r += t; }
        bsum[blockIdx.x] = r;
    }
    __syncthreads();
    if (i < N) partial[i] = (s - v) + ws[wid];
}

__global__ void scan2_kernel(int* __restrict__ bsum, int NB) {
    __shared__ int ws[4];
    int t = threadIdx.x;
    int v = (t < NB) ? bsum[t] : 0;
    int lane = t & 63;
    int wid = t >> 6;
    int s = v;
#pragma unroll
    for (int d = 1; d < 64; d <<= 1) {
        int u = __shfl_up(s, d, 64);
        if (lane >= d) s += u;
    }
    if (lane == 63) ws[wid] = s;
    __syncthreads();
    if (t == 0) {
        int r = 0;
        for (int w = 0; w < 4; w++) { int u = ws[w]; ws[w] = r; r += u; }
    }
    __syncthreads();
    if (t < NB) bsum[t] = (s - v) + ws[wid];
}

__global__ void scan3_kernel(const int* __restrict__ partial,
                             const int* __restrict__ bsum,
                             int* __restrict__ off,
                             int* __restrict__ cursor, int N) {
    int i = blockIdx.x * 256 + threadIdx.x;
    if (i >= N) return;
    int o = partial[i] + bsum[i >> 8];
    off[i] = o;
    cursor[i] = o;
}

// ---- bucket cursors: bucket b's staging span starts at off[b<<9] ----
__global__ void bcur_init_kernel(const int* __restrict__ off,
                                 int* __restrict__ bcur, int nbuck) {
    int b = threadIdx.x;
    if (b < nbuck) bcur[b] = off[b << 9];
}

// ---- partA: bucket-partition edges by dst>>9, LDS-staged ----
__global__ __launch_bounds__(256) void partA_kernel(
        const float* __restrict__ K, const int* __restrict__ ei,
        const int* __restrict__ flagp, int* __restrict__ bcur,
        int4* __restrict__ staging, int E) {
    __shared__ int cnt[NBMAX];
    __shared__ int bexc[NBMAX];
    __shared__ int gbase[NBMAX];
    __shared__ int scanbuf[NBMAX];
    __shared__ int4 stage[CHUNK];     // 32 KB

    int flag = *flagp;
    int e0 = blockIdx.x * CHUNK;
    int tot = min(CHUNK, E - e0);

    for (int b = threadIdx.x; b < NBMAX; b += 256) cnt[b] = 0;
    __syncthreads();

    int  myslot[CHUNK / 256];
    int  mybk[CHUNK / 256];
    int4 myrec[CHUNK / 256];
#pragma unroll
    for (int it = 0; it < CHUNK / 256; ++it) {
        int e = e0 + it * 256 + threadIdx.x;
        mybk[it] = -1;
        if (e < E) {
            int src, dst;
            load_edge(ei, e, E, flag, src, dst);
            int bk = dst >> 9;
            mybk[it] = bk;
            myrec[it] = make_int4(src, __float_as_int(K[e]),
                                  __float_as_int(K[E + e]), dst);
            myslot[it] = atomicAdd(&cnt[bk], 1);
        }
    }
    __syncthreads();

    // inclusive scan of cnt -> scanbuf
    if (threadIdx.x < NBMAX) scanbuf[threadIdx.x] = cnt[threadIdx.x];
    __syncthreads();
    for (int d = 1; d < NBMAX; d <<= 1) {
        int v = 0;
        if (threadIdx.x < NBMAX && threadIdx.x >= d) v = scanbuf[threadIdx.x - d];
        __syncthreads();
        if (threadIdx.x < NBMAX) scanbuf[threadIdx.x] += v;
        __syncthreads();
    }
    if (threadIdx.x < NBMAX) {
        int c = cnt[threadIdx.x];
        bexc[threadIdx.x] = scanbuf[threadIdx.x] - c;
        gbase[threadIdx.x] = c ? atomicAdd(&bcur[threadIdx.x], c) : 0;
    }
    __syncthreads();

#pragma unroll
    for (int it = 0; it < CHUNK / 256; ++it) {
        if (mybk[it] >= 0) stage[bexc[mybk[it]] + myslot[it]] = myrec[it];
    }
    __syncthreads();

    for (int i = threadIdx.x; i < tot; i += 256) {
        int4 r = stage[i];
        int bk = r.w >> 9;
        staging[gbase[bk] + (i - bexc[bk])] = r;
    }
}

// ---- partB: within-bucket final placement (writes stay in a ~195 KB span) ----
__global__ void partB_kernel(const int4* __restrict__ staging,
                             int* __restrict__ cursor,
                             int* __restrict__ srcS,
                             float2* __restrict__ kS, int E) {
    int i = blockIdx.x * 256 + threadIdx.x;
    if (i >= E) return;
    int4 r = staging[i];
    int pos = atomicAdd(&cursor[r.w], 1);
    srcS[pos] = r.x;
    kS[pos] = make_float2(__int_as_float(r.y), __int_as_float(r.z));
}

// ---- fallback single-pass scatter (if ws too small for staging) ----
__global__ void scatter_kernel(const float* __restrict__ K,
                               const int* __restrict__ ei,
                               const int* __restrict__ flagp,
                               int* __restrict__ cursor,
                               int* __restrict__ srcS,
                               float2* __restrict__ kS, int E) {
    int e = blockIdx.x * 256 + threadIdx.x;
    if (e >= E) return;
    int flag = *flagp;
    int src, dst;
    load_edge(ei, e, E, flag, src, dst);
    int pos = atomicAdd(&cursor[dst], 1);
    srcS[pos] = src;
    kS[pos] = make_float2(K[e], K[E + e]);
}

// ---- conv1 + MLP1 fused: one HALF-WAVE (32 lanes) per node ----
__global__ void conv1_mlp1_kernel(const float* __restrict__ x,
                                  const int* __restrict__ srcS,
                                  const float2* __restrict__ kS,
                                  const int* __restrict__ off,
                                  const int* __restrict__ counts,
                                  const float* __restrict__ W1,
                                  const float* __restrict__ b1,
                                  float* __restrict__ h1, int N) {
    __shared__ float w[32 * 32];
    __shared__ float bsh[32];
    for (int i = threadIdx.x; i < 1024; i += 256) w[i] = W1[i];
    if (threadIdx.x < 32) bsh[threadIdx.x] = b1[threadIdx.x];
    __syncthreads();

    int hw = threadIdx.x >> 5;
    int lane = threadIdx.x & 31;
    int node = blockIdx.x * 8 + hw;
    if (node >= N) return;

    int ch = lane & 15;
    int kq = lane >> 4;
    int start = off[node];
    int deg = counts[node];

    float acc = 0.0f;
    int j = 0;
    for (; j + 4 <= deg; j += 4) {
        int p = start + j;
        int s0 = srcS[p + 0];
        int s1 = srcS[p + 1];
        int s2 = srcS[p + 2];
        int s3 = srcS[p + 3];
        float2 ka = kS[p + 0];
        float2 kb = kS[p + 1];
        float2 kc = kS[p + 2];
        float2 kd = kS[p + 3];
        float x0 = x[s0 * 16 + ch];
        float x1 = x[s1 * 16 + ch];
        float x2 = x[s2 * 16 + ch];
        float x3 = x[s3 * 16 + ch];
        acc += (kq ? ka.y : ka.x) * x0;
        acc += (kq ? kb.y : kb.x) * x1;
        acc += (kq ? kc.y : kc.x) * x2;
        acc += (kq ? kd.y : kd.x) * x3;
    }
    for (; j < deg; ++j) {
        int p = start + j;
        int s = srcS[p];
        float2 kk = kS[p];
        acc += (kq ? kk.y : kk.x) * x[s * 16 + ch];
    }

    float o = bsh[lane];
#pragma unroll
    for (int i = 0; i < 32; i++) o += __shfl(acc, i, 32) * w[i * 32 + lane];
    o = fmaxf(o, 0.0f);

    float ss = o * o;
#pragma unroll
    for (int m = 16; m >= 1; m >>= 1) ss += __shfl_xor(ss, m, 32);
    float nrm = sqrtf(ss);
    h1[node * 32 + lane] = o / fmaxf(nrm, EPSV);
}

// ---- conv2: one wave per node, 64 output channels, unroll-4 gather ----
__global__ void conv2_gather_kernel(const float* __restrict__ h1,
                                    const int* __restrict__ srcS,
                                    const float2* __restrict__ kS,
                                    const int* __restrict__ off,
                                    const int* __restrict__ counts,
                                    float* __restrict__ h2, int N) {
    int wid = threadIdx.x >> 6;
    int lane = threadIdx.x & 63;
    int node = blockIdx.x * 4 + wid;
    if (node >= N) return;

    int ch = lane & 31;
    int kq = lane >> 5;
    int start = off[node];
    int deg = counts[node];

    float acc = 0.0f;
    int j = 0;
    for (; j + 4 <= deg; j += 4) {
        int p = start + j;
        int s0 = srcS[p + 0];
        int s1 = srcS[p + 1];
        int s2 = srcS[p + 2];
        int s3 = srcS[p + 3];
        float2 ka = kS[p + 0];
        float2 kb = kS[p + 1];
        float2 kc = kS[p + 2];
        float2 kd = kS[p + 3];
        float v0 = h1[s0 * 32 + ch];
        float v1 = h1[s1 * 32 + ch];
        float v2 = h1[s2 * 32 + ch];
        float v3 = h1[s3 * 32 + ch];
        acc += (kq ? ka.y : ka.x) * v0;
        acc += (kq ? kb.y : kb.x) * v1;
        acc += (kq ? kc.y : kc.x) * v2;
        acc += (kq ? kd.y : kd.x) * v3;
    }
    for (; j < deg; ++j) {
        int p = start + j;
        int s = srcS[p];
        float2 kk = kS[p];
        acc += (kq ? kk.y : kk.x) * h1[s * 32 + ch];
    }
    h2[node * 64 + kq * 32 + ch] = acc;
}

// ---- MLP2 register-tiled: 64 nodes/block, 256 threads ----
__global__ __launch_bounds__(256) void mlp2_kernel(
        const float* __restrict__ h2,
        const float* __restrict__ W2a,
        const float* __restrict__ b2a,
        const float* __restrict__ W2b,
        const float* __restrict__ b2b,
        float* __restrict__ out, int N) {
    __shared__ float xs[64 * 68];
    __shared__ float hs[128 * 68];

    int tid = threadIdx.x;
    int n0 = blockIdx.x * 64;

#pragma unroll
    for (int it = 0; it < 4; ++it) {
        int idx = tid + it * 256;
        int n = idx >> 4;
        int c4 = (idx & 15) * 4;
        float4 v = make_float4(0.f, 0.f, 0.f, 0.f);
        if (n0 + n < N) v = *(const float4*)&h2[(size_t)(n0 + n) * 64 + c4];
        xs[(c4 + 0) * 68 + n] = v.x;
        xs[(c4 + 1) * 68 + n] = v.y;
        xs[(c4 + 2) * 68 + n] = v.z;
        xs[(c4 + 3) * 68 + n] = v.w;
    }
    __syncthreads();

    int rg = tid >> 4;
    int cg = tid & 15;

    float acc[4][8];
#pragma unroll
    for (int j = 0; j < 4; j++)
#pragma unroll
        for (int i = 0; i < 8; i++) acc[j][i] = 0.0f;

    for (int k = 0; k < 64; ++k) {
        float4 xv = *(const float4*)&xs[k * 68 + rg * 4];
        float4 w0 = *(const float4*)&W2a[k * 128 + cg * 8];
        float4 w1 = *(const float4*)&W2a[k * 128 + cg * 8 + 4];
        float wv[8] = {w0.x, w0.y, w0.z, w0.w, w1.x, w1.y, w1.z, w1.w};
        float xr[4] = {xv.x, xv.y, xv.z, xv.w};
#pragma unroll
        for (int j = 0; j < 4; j++)
#pragma unroll
            for (int i = 0; i < 8; i++) acc[j][i] += xr[j] * wv[i];
    }

#pragma unroll
    for (int i = 0; i < 8; i++) {
        float bi = b2a[cg * 8 + i];
#pragma unroll
        for (int j = 0; j < 4; j++) {
            float hv = fmaxf(acc[j][i] + bi, 0.0f);
            hs[(cg * 8 + i) * 68 + rg * 4 + j] = hv;
        }
    }
    __syncthreads();

    float a2[4][4];
#pragma unroll
    for (int j = 0; j < 4; j++)
#pragma unroll
        for (int i = 0; i < 4; i++) a2[j][i] = 0.0f;

    for (int k = 0; k < 128; ++k) {
        float4 hv = *(const float4*)&hs[k * 68 + rg * 4];
        float4 w = *(const float4*)&W2b[k * 64 + cg * 4];
        float wv[4] = {w.x, w.y, w.z, w.w};
        float hr[4] = {hv.x, hv.y, hv.z, hv.w};
#pragma unroll
        for (int j = 0; j < 4; j++)
#pragma unroll
            for (int i = 0; i < 4; i++) a2[j][i] += hr[j] * wv[i];
    }

#pragma unroll
    for (int i = 0; i < 4; i++) {
        float bi = b2b[cg * 4 + i];
#pragma unroll
        for (int j = 0; j < 4; j++) a2[j][i] += bi;
    }

#pragma unroll
    for (int j = 0; j < 4; j++) {
        float ss = a2[j][0] * a2[j][0] + a2[j][1] * a2[j][1] +
                   a2[j][2] * a2[j][2] + a2[j][3] * a2[j][3];
#pragma unroll
        for (int m = 1; m < 16; m <<= 1) ss += __shfl_xor(ss, m, 64);
        float invn = 1.0f / fmaxf(sqrtf(ss), EPSV);
        int n = n0 + rg * 4 + j;
        if (n < N) {
            float4 o = make_float4(a2[j][0] * invn, a2[j][1] * invn,
                                   a2[j][2] * invn, a2[j][3] * invn);
            *(float4*)&out[(size_t)n * 64 + cg * 4] = o;
        }
    }
}

extern "C" void kernel_launch(void* const* d_in, const int* in_sizes, int n_in,
                              void* d_out, int out_size, void* d_ws, size_t ws_size,
                              hipStream_t stream) {
    const float* x   = (const float*)d_in[0];
    const float* K   = (const float*)d_in[1];
    const int*   ei  = (const int*)d_in[2];
    const float* W1  = (const float*)d_in[3];
    const float* b1  = (const float*)d_in[4];
    const float* W2a = (const float*)d_in[5];
    const float* b2a = (const float*)d_in[6];
    const float* W2b = (const float*)d_in[7];
    const float* b2b = (const float*)d_in[8];
    float* out = (float*)d_out;

    const int D  = 16;
    const int NK = 2;
    const int N  = in_sizes[0] / D;        // 50000
    const int E  = in_sizes[1] / NK;       // 1600000
    const int NB = (N + 255) / 256;        // scan blocks
    const int nbuck = (N + 511) >> 9;      // <= 128

    // workspace layout:
    //   region A: max(E*16 [staging int4], N*96*4 [h1|h2]) bytes (overlaid:
    //             staging is dead before h1/h2 are written)
    //   then: srcS[E] | kS[E] (float2) | counts[N] | off[N] | cursor[N] |
    //         partial[N] | bsum[256] | bcur[128] | flag[1]
    size_t regionA = (size_t)E * 16;
    size_t hbytes  = (size_t)N * 96 * 4;
    if (hbytes > regionA) regionA = hbytes;

    float* h1       = (float*)d_ws;
    float* h2       = h1 + (size_t)N * 32;
    int4* staging   = (int4*)d_ws;
    int* srcS       = (int*)((char*)d_ws + regionA);
    float2* kS      = (float2*)(srcS + (size_t)E);
    int* counts     = (int*)(kS + (size_t)E);
    int* off        = counts + N;
    int* cursor     = off + N;
    int* partial    = cursor + N;
    int* bsum       = partial + N;
    int* bcur       = bsum + 256;
    int* flag       = bcur + NBMAX;

    size_t needed = ((char*)(flag + 1)) - ((char*)d_ws);
    bool two_pass = (needed <= ws_size);
    if (!two_pass) {
        // compact layout without staging (fallback): srcS directly after h2
        srcS    = (int*)(h2 + (size_t)N * 64);
        kS      = (float2*)(srcS + (size_t)E);
        counts  = (int*)(kS + (size_t)E);
        off     = counts + N;
        cursor  = off + N;
        partial = cursor + N;
        bsum    = partial + N;
        bcur    = bsum + 256;
        flag    = bcur + NBMAX;
    }

    hipMemsetAsync(counts, 0, (size_t)N * sizeof(int), stream);
    detect_i64_kernel<<<1, 64, 0, stream>>>(ei, flag);

    int eblocks = (E + 255) / 256;
    hist_kernel<<<eblocks, 256, 0, stream>>>(ei, flag, counts, E);
    scan1_kernel<<<NB, 256, 0, stream>>>(counts, partial, bsum, N);
    scan2_kernel<<<1, 256, 0, stream>>>(bsum, NB);
    scan3_kernel<<<NB, 256, 0, stream>>>(partial, bsum, off, cursor, N);

    if (two_pass) {
        bcur_init_kernel<<<1, NBMAX, 0, stream>>>(off, bcur, nbuck);
        int ablocks = (E + CHUNK - 1) / CHUNK;
        partA_kernel<<<ablocks, 256, 0, stream>>>(K, ei, flag, bcur, staging, E);
        partB_kernel<<<eblocks, 256, 0, stream>>>(staging, cursor, srcS, kS, E);
    } else {
        scatter_kernel<<<eblocks, 256, 0, stream>>>(K, ei, flag, cursor,
                                                    srcS, kS, E);
    }

    conv1_mlp1_kernel<<<(N + 7) / 8, 256, 0, stream>>>(x, srcS, kS, off, counts,
                                                       W1, b1, h1, N);
    conv2_gather_kernel<<<(N + 3) / 4, 256, 0, stream>>>(h1, srcS, kS, off,
                                                         counts, h2, N);
    mlp2_kernel<<<(N + 63) / 64, 256, 0, stream>>>(h2, W2a, b2a, W2b, b2b,
                                                   out, N);
}

// Round 6
// 264.048 us; speedup vs baseline: 2.7733x; 1.1775x over previous
//
#include <hip/hip_runtime.h>
#include <hip/hip_bf16.h>

// Pipeline (N=50000, E=1.6M, D=16, NK=2):
//   bhist: LDS-private bucket histogram (bucket = dst>>9), no global atomics
//   bscan: column-sum + scan 128 buckets -> bbase/bcur
//   partA: bucket-partition edges into staging (LDS-staged, coalesced writes)
//   partB: one block per bucket: LDS per-node hist + scan (-> off/counts),
//          LDS-cursor placement; writes stay in bucket's ~195KB span (L2)
//   conv1+mlp1 fused: h1[N,32] = l2norm(relu(conv(x) @ W1 + b1)), half-wave/node
//   conv2:            h2[N,64] = conv(h1), 1 wave/node, unroll-4 gather
//   mlp2:             out = l2norm(relu(h2@W2a+b2a)@W2b + b2b)  [reg-tiled GEMM]

#define EPSV 1e-12f
#define CHUNK 2048      // edges per partA block
#define NBMAX 128       // bucket slots (nbuck = ceil(N/512) = 98 <= 128)
#define BNODES 512      // nodes per bucket (dst >> 9)

// ---- detect whether edge_index buffer is int64 (odd int32 words all zero) ----
__global__ void detect_i64_kernel(const int* ei, int* flag) {
    int lane = threadIdx.x;
    int nonzero = 0;
    for (int i = lane; i < 1024; i += 64) {
        if (ei[2 * i + 1] != 0) nonzero = 1;
    }
    unsigned long long b = __ballot(nonzero);
    if (lane == 0) *flag = (b == 0ull) ? 1 : 0;   // 1 => int64 layout
}

__device__ __forceinline__ void load_edge(const int* ei, int e, int E, int flag,
                                          int& src, int& dst) {
    if (flag) {            // int64 storage: low words at even int32 indices
        src = ei[2 * e];
        dst = ei[2 * E + 2 * e];
    } else {               // int32 storage
        src = ei[e];
        dst = ei[E + e];
    }
}

// ---- bucket histogram: LDS-privatized, one cntmat row per block ----
__global__ __launch_bounds__(256) void bhist_kernel(
        const int* __restrict__ ei, const int* __restrict__ flagp,
        int* __restrict__ cntmat, int E) {
    __shared__ int l[NBMAX];
    if (threadIdx.x < NBMAX) l[threadIdx.x] = 0;
    __syncthreads();
    int flag = *flagp;
    int stride = gridDim.x * 256;
    for (int e = blockIdx.x * 256 + threadIdx.x; e < E; e += stride) {
        int dst = flag ? ei[2 * E + 2 * e] : ei[E + e];
        atomicAdd(&l[dst >> 9], 1);
    }
    __syncthreads();
    if (threadIdx.x < NBMAX) cntmat[blockIdx.x * NBMAX + threadIdx.x] = l[threadIdx.x];
}

// ---- column-sum cntmat + exclusive scan of bucket counts ----
__global__ void bscan_kernel(const int* __restrict__ cntmat,
                             int* __restrict__ bbase, int* __restrict__ bcur,
                             int nbuck, int E, int nrows) {
    __shared__ int s[NBMAX];
    int t = threadIdx.x;            // blockDim = NBMAX
    int c = 0;
    for (int i = 0; i < nrows; ++i) c += cntmat[i * NBMAX + t];
    s[t] = c;
    __syncthreads();
    for (int d = 1; d < NBMAX; d <<= 1) {
        int v = (t >= d) ? s[t - d] : 0;
        __syncthreads();
        s[t] += v;
        __syncthreads();
    }
    int excl = s[t] - c;
    if (t < nbuck) { bbase[t] = excl; bcur[t] = excl; }
    if (t == 0) bbase[nbuck] = E;
}

// ---- partA: bucket-partition edges by dst>>9, LDS-staged ----
__global__ __launch_bounds__(256) void partA_kernel(
        const float* __restrict__ K, const int* __restrict__ ei,
        const int* __restrict__ flagp, int* __restrict__ bcur,
        int4* __restrict__ staging, int E) {
    __shared__ int cnt[NBMAX];
    __shared__ int bexc[NBMAX];
    __shared__ int gbase[NBMAX];
    __shared__ int scanbuf[NBMAX];
    __shared__ int4 stage[CHUNK];     // 32 KB

    int flag = *flagp;
    int e0 = blockIdx.x * CHUNK;
    int tot = min(CHUNK, E - e0);

    for (int b = threadIdx.x; b < NBMAX; b += 256) cnt[b] = 0;
    __syncthreads();

    int  myslot[CHUNK / 256];
    int  mybk[CHUNK / 256];
    int4 myrec[CHUNK / 256];
#pragma unroll
    for (int it = 0; it < CHUNK / 256; ++it) {
        int e = e0 + it * 256 + threadIdx.x;
        mybk[it] = -1;
        if (e < E) {
            int src, dst;
            load_edge(ei, e, E, flag, src, dst);
            int bk = dst >> 9;
            mybk[it] = bk;
            myrec[it] = make_int4(src, __float_as_int(K[e]),
                                  __float_as_int(K[E + e]), dst);
            myslot[it] = atomicAdd(&cnt[bk], 1);
        }
    }
    __syncthreads();

    if (threadIdx.x < NBMAX) scanbuf[threadIdx.x] = cnt[threadIdx.x];
    __syncthreads();
    for (int d = 1; d < NBMAX; d <<= 1) {
        int v = 0;
        if (threadIdx.x < NBMAX && threadIdx.x >= d) v = scanbuf[threadIdx.x - d];
        __syncthreads();
        if (threadIdx.x < NBMAX) scanbuf[threadIdx.x] += v;
        __syncthreads();
    }
    if (threadIdx.x < NBMAX) {
        int c = cnt[threadIdx.x];
        bexc[threadIdx.x] = scanbuf[threadIdx.x] - c;
        gbase[threadIdx.x] = c ? atomicAdd(&bcur[threadIdx.x], c) : 0;
    }
    __syncthreads();

#pragma unroll
    for (int it = 0; it < CHUNK / 256; ++it) {
        if (mybk[it] >= 0) stage[bexc[mybk[it]] + myslot[it]] = myrec[it];
    }
    __syncthreads();

    for (int i = threadIdx.x; i < tot; i += 256) {
        int4 r = stage[i];
        int bk = r.w >> 9;
        staging[gbase[bk] + (i - bexc[bk])] = r;
    }
}

// ---- partB: one block per bucket; LDS hist+scan -> off/counts; place ----
__global__ __launch_bounds__(1024) void partB_kernel(
        const int4* __restrict__ staging, const int* __restrict__ bbase,
        int* __restrict__ off, int* __restrict__ counts,
        int* __restrict__ srcS, float2* __restrict__ kS, int N) {
    __shared__ int lcnt[BNODES];
    __shared__ int lscan[BNODES];

    int b = blockIdx.x;
    int nodeBase = b << 9;
    int s0 = bbase[b];
    int s1 = bbase[b + 1];
    int t = threadIdx.x;

    if (t < BNODES) lcnt[t] = 0;
    __syncthreads();

    for (int i = s0 + t; i < s1; i += 1024) {
        int4 r = staging[i];
        atomicAdd(&lcnt[r.w - nodeBase], 1);
    }
    __syncthreads();

    if (t < BNODES) lscan[t] = lcnt[t];
    __syncthreads();
    for (int d = 1; d < BNODES; d <<= 1) {
        int v = 0;
        if (t < BNODES && t >= d) v = lscan[t - d];
        __syncthreads();
        if (t < BNODES) lscan[t] += v;
        __syncthreads();
    }
    if (t < BNODES) {
        int node = nodeBase + t;
        if (node < N) {
            int c = lcnt[t];
            int o = s0 + lscan[t] - c;   // exclusive offset, absolute
            off[node] = o;
            counts[node] = c;
            lcnt[t] = o;                 // becomes the cursor
        }
    }
    __syncthreads();

    for (int i = s0 + t; i < s1; i += 1024) {
        int4 r = staging[i];
        int pos = atomicAdd(&lcnt[r.w - nodeBase], 1);
        srcS[pos] = r.x;
        kS[pos] = make_float2(__int_as_float(r.y), __int_as_float(r.z));
    }
}

// ---- conv1 + MLP1 fused: one HALF-WAVE (32 lanes) per node ----
__global__ void conv1_mlp1_kernel(const float* __restrict__ x,
                                  const int* __restrict__ srcS,
                                  const float2* __restrict__ kS,
                                  const int* __restrict__ off,
                                  const int* __restrict__ counts,
                                  const float* __restrict__ W1,
                                  const float* __restrict__ b1,
                                  float* __restrict__ h1, int N) {
    __shared__ float w[32 * 32];
    __shared__ float bsh[32];
    for (int i = threadIdx.x; i < 1024; i += 256) w[i] = W1[i];
    if (threadIdx.x < 32) bsh[threadIdx.x] = b1[threadIdx.x];
    __syncthreads();

    int hw = threadIdx.x >> 5;
    int lane = threadIdx.x & 31;
    int node = blockIdx.x * 8 + hw;
    if (node >= N) return;

    int ch = lane & 15;
    int kq = lane >> 4;
    int start = off[node];
    int deg = counts[node];

    float acc = 0.0f;
    int j = 0;
    for (; j + 4 <= deg; j += 4) {
        int p = start + j;
        int s0 = srcS[p + 0];
        int s1 = srcS[p + 1];
        int s2 = srcS[p + 2];
        int s3 = srcS[p + 3];
        float2 ka = kS[p + 0];
        float2 kb = kS[p + 1];
        float2 kc = kS[p + 2];
        float2 kd = kS[p + 3];
        float x0 = x[s0 * 16 + ch];
        float x1 = x[s1 * 16 + ch];
        float x2 = x[s2 * 16 + ch];
        float x3 = x[s3 * 16 + ch];
        acc += (kq ? ka.y : ka.x) * x0;
        acc += (kq ? kb.y : kb.x) * x1;
        acc += (kq ? kc.y : kc.x) * x2;
        acc += (kq ? kd.y : kd.x) * x3;
    }
    for (; j < deg; ++j) {
        int p = start + j;
        int s = srcS[p];
        float2 kk = kS[p];
        acc += (kq ? kk.y : kk.x) * x[s * 16 + ch];
    }

    float o = bsh[lane];
#pragma unroll
    for (int i = 0; i < 32; i++) o += __shfl(acc, i, 32) * w[i * 32 + lane];
    o = fmaxf(o, 0.0f);

    float ss = o * o;
#pragma unroll
    for (int m = 16; m >= 1; m >>= 1) ss += __shfl_xor(ss, m, 32);
    float nrm = sqrtf(ss);
    h1[node * 32 + lane] = o / fmaxf(nrm, EPSV);
}

// ---- conv2: one wave per node, 64 output channels, unroll-4 gather ----
__global__ void conv2_gather_kernel(const float* __restrict__ h1,
                                    const int* __restrict__ srcS,
                                    const float2* __restrict__ kS,
                                    const int* __restrict__ off,
                                    const int* __restrict__ counts,
                                    float* __restrict__ h2, int N) {
    int wid = threadIdx.x >> 6;
    int lane = threadIdx.x & 63;
    int node = blockIdx.x * 4 + wid;
    if (node >= N) return;

    int ch = lane & 31;
    int kq = lane >> 5;
    int start = off[node];
    int deg = counts[node];

    float acc = 0.0f;
    int j = 0;
    for (; j + 4 <= deg; j += 4) {
        int p = start + j;
        int s0 = srcS[p + 0];
        int s1 = srcS[p + 1];
        int s2 = srcS[p + 2];
        int s3 = srcS[p + 3];
        float2 ka = kS[p + 0];
        float2 kb = kS[p + 1];
        float2 kc = kS[p + 2];
        float2 kd = kS[p + 3];
        float v0 = h1[s0 * 32 + ch];
        float v1 = h1[s1 * 32 + ch];
        float v2 = h1[s2 * 32 + ch];
        float v3 = h1[s3 * 32 + ch];
        acc += (kq ? ka.y : ka.x) * v0;
        acc += (kq ? kb.y : kb.x) * v1;
        acc += (kq ? kc.y : kc.x) * v2;
        acc += (kq ? kd.y : kd.x) * v3;
    }
    for (; j < deg; ++j) {
        int p = start + j;
        int s = srcS[p];
        float2 kk = kS[p];
        acc += (kq ? kk.y : kk.x) * h1[s * 32 + ch];
    }
    h2[node * 64 + kq * 32 + ch] = acc;
}

// ---- MLP2 register-tiled: 64 nodes/block, 256 threads ----
__global__ __launch_bounds__(256) void mlp2_kernel(
        const float* __restrict__ h2,
        const float* __restrict__ W2a,
        const float* __restrict__ b2a,
        const float* __restrict__ W2b,
        const float* __restrict__ b2b,
        float* __restrict__ out, int N) {
    __shared__ float xs[64 * 68];
    __shared__ float hs[128 * 68];

    int tid = threadIdx.x;
    int n0 = blockIdx.x * 64;

#pragma unroll
    for (int it = 0; it < 4; ++it) {
        int idx = tid + it * 256;
        int n = idx >> 4;
        int c4 = (idx & 15) * 4;
        float4 v = make_float4(0.f, 0.f, 0.f, 0.f);
        if (n0 + n < N) v = *(const float4*)&h2[(size_t)(n0 + n) * 64 + c4];
        xs[(c4 + 0) * 68 + n] = v.x;
        xs[(c4 + 1) * 68 + n] = v.y;
        xs[(c4 + 2) * 68 + n] = v.z;
        xs[(c4 + 3) * 68 + n] = v.w;
    }
    __syncthreads();

    int rg = tid >> 4;
    int cg = tid & 15;

    float acc[4][8];
#pragma unroll
    for (int j = 0; j < 4; j++)
#pragma unroll
        for (int i = 0; i < 8; i++) acc[j][i] = 0.0f;

    for (int k = 0; k < 64; ++k) {
        float4 xv = *(const float4*)&xs[k * 68 + rg * 4];
        float4 w0 = *(const float4*)&W2a[k * 128 + cg * 8];
        float4 w1 = *(const float4*)&W2a[k * 128 + cg * 8 + 4];
        float wv[8] = {w0.x, w0.y, w0.z, w0.w, w1.x, w1.y, w1.z, w1.w};
        float xr[4] = {xv.x, xv.y, xv.z, xv.w};
#pragma unroll
        for (int j = 0; j < 4; j++)
#pragma unroll
            for (int i = 0; i < 8; i++) acc[j][i] += xr[j] * wv[i];
    }

#pragma unroll
    for (int i = 0; i < 8; i++) {
        float bi = b2a[cg * 8 + i];
#pragma unroll
        for (int j = 0; j < 4; j++) {
            float hv = fmaxf(acc[j][i] + bi, 0.0f);
            hs[(cg * 8 + i) * 68 + rg * 4 + j] = hv;
        }
    }
    __syncthreads();

    float a2[4][4];
#pragma unroll
    for (int j = 0; j < 4; j++)
#pragma unroll
        for (int i = 0; i < 4; i++) a2[j][i] = 0.0f;

    for (int k = 0; k < 128; ++k) {
        float4 hv = *(const float4*)&hs[k * 68 + rg * 4];
        float4 w = *(const float4*)&W2b[k * 64 + cg * 4];
        float wv[4] = {w.x, w.y, w.z, w.w};
        float hr[4] = {hv.x, hv.y, hv.z, hv.w};
#pragma unroll
        for (int j = 0; j < 4; j++)
#pragma unroll
            for (int i = 0; i < 4; i++) a2[j][i] += hr[j] * wv[i];
    }

#pragma unroll
    for (int i = 0; i < 4; i++) {
        float bi = b2b[cg * 4 + i];
#pragma unroll
        for (int j = 0; j < 4; j++) a2[j][i] += bi;
    }

#pragma unroll
    for (int j = 0; j < 4; j++) {
        float ss = a2[j][0] * a2[j][0] + a2[j][1] * a2[j][1] +
                   a2[j][2] * a2[j][2] + a2[j][3] * a2[j][3];
#pragma unroll
        for (int m = 1; m < 16; m <<= 1) ss += __shfl_xor(ss, m, 64);
        float invn = 1.0f / fmaxf(sqrtf(ss), EPSV);
        int n = n0 + rg * 4 + j;
        if (n < N) {
            float4 o = make_float4(a2[j][0] * invn, a2[j][1] * invn,
                                   a2[j][2] * invn, a2[j][3] * invn);
            *(float4*)&out[(size_t)n * 64 + cg * 4] = o;
        }
    }
}

extern "C" void kernel_launch(void* const* d_in, const int* in_sizes, int n_in,
                              void* d_out, int out_size, void* d_ws, size_t ws_size,
                              hipStream_t stream) {
    const float* x   = (const float*)d_in[0];
    const float* K   = (const float*)d_in[1];
    const int*   ei  = (const int*)d_in[2];
    const float* W1  = (const float*)d_in[3];
    const float* b1  = (const float*)d_in[4];
    const float* W2a = (const float*)d_in[5];
    const float* b2a = (const float*)d_in[6];
    const float* W2b = (const float*)d_in[7];
    const float* b2b = (const float*)d_in[8];
    float* out = (float*)d_out;

    const int D  = 16;
    const int NK = 2;
    const int N  = in_sizes[0] / D;        // 50000
    const int E  = in_sizes[1] / NK;       // 1600000
    const int nbuck = (N + 511) >> 9;      // 98 <= NBMAX
    const int HROWS = 256;                 // bhist blocks

    // workspace layout:
    //   region A: max(E*16 [staging int4], N*96*4 [h1|h2]) (overlaid: staging
    //             is dead before h1/h2 are written)
    //   then: srcS[E] | kS[E] (float2) | counts[N] | off[N] |
    //         cntmat[HROWS*NBMAX] | bbase[NBMAX+1] | bcur[NBMAX] | flag[1]
    size_t regionA = (size_t)E * 16;
    size_t hbytes  = (size_t)N * 96 * 4;
    if (hbytes > regionA) regionA = hbytes;

    float* h1       = (float*)d_ws;
    float* h2       = h1 + (size_t)N * 32;
    int4* staging   = (int4*)d_ws;
    int* srcS       = (int*)((char*)d_ws + regionA);
    float2* kS      = (float2*)(srcS + (size_t)E);
    int* counts     = (int*)(kS + (size_t)E);
    int* off        = counts + N;
    int* cntmat     = off + N;
    int* bbase      = cntmat + HROWS * NBMAX;
    int* bcur       = bbase + NBMAX + 1;
    int* flag       = bcur + NBMAX;

    detect_i64_kernel<<<1, 64, 0, stream>>>(ei, flag);
    bhist_kernel<<<HROWS, 256, 0, stream>>>(ei, flag, cntmat, E);
    bscan_kernel<<<1, NBMAX, 0, stream>>>(cntmat, bbase, bcur, nbuck, E, HROWS);

    int ablocks = (E + CHUNK - 1) / CHUNK;
    partA_kernel<<<ablocks, 256, 0, stream>>>(K, ei, flag, bcur, staging, E);
    partB_kernel<<<nbuck, 1024, 0, stream>>>(staging, bbase, off, counts,
                                             srcS, kS, N);

    conv1_mlp1_kernel<<<(N + 7) / 8, 256, 0, stream>>>(x, srcS, kS, off, counts,
                                                       W1, b1, h1, N);
    conv2_gather_kernel<<<(N + 3) / 4, 256, 0, stream>>>(h1, srcS, kS, off,
                                                         counts, h2, N);
    mlp2_kernel<<<(N + 63) / 64, 256, 0, stream>>>(h2, W2a, b2a, W2b, b2b,
                                                   out, N);
}